// Round 5
// baseline (981.268 us; speedup 1.0000x reference)
//
#include <hip/hip_runtime.h>
#include <math.h>

#define NN 100000
#define NE 1600000
#define NB 782      // dst buckets of 128 nodes
#define BCAP 3072   // bucket capacity (mean ~2046, 22 sigma safe)
#define BKBLK 128   // blocks in bucket build
#define BKCHUNK (NE / BKBLK)  // 12500 edges per block

typedef unsigned short ushort_t;
typedef unsigned int uint_t;
typedef __attribute__((ext_vector_type(8))) short bf16x8;
typedef __attribute__((ext_vector_type(8))) unsigned short u16x8;
typedef __attribute__((ext_vector_type(4))) float f32x4;

__device__ __forceinline__ ushort_t f2bf(float f) {
  uint_t u = __float_as_uint(f);
  u = (u + 0x7fffu + ((u >> 16) & 1u)) >> 16;   // round-to-nearest-even
  return (ushort_t)u;
}
__device__ __forceinline__ float bf2f(ushort_t h) {
  return __uint_as_float((uint_t)h << 16);
}

// ---------------- setup: bucketed CSR build (histogram + reserve + write) ----------------

__global__ __launch_bounds__(512) void bucketA_k(const int* __restrict__ src, const int* __restrict__ dst,
                                                 int* __restrict__ bcnt, uint_t* __restrict__ pairs) {
  __shared__ int h[NB];
  const int t = threadIdx.x;
  const int e0 = blockIdx.x * BKCHUNK;
  for (int b = t; b < NB; b += 512) h[b] = 0;
  __syncthreads();
  for (int i = t; i < BKCHUNK; i += 512) atomicAdd(&h[dst[e0 + i] >> 7], 1);
  __syncthreads();
  for (int b = t; b < NB; b += 512) h[b] = atomicAdd(&bcnt[b], h[b]);
  __syncthreads();
  for (int i = t; i < BKCHUNK; i += 512) {
    int s = src[e0 + i], d = dst[e0 + i];
    int b = d >> 7;
    int pos = atomicAdd(&h[b], 1);
    if (pos < BCAP) pairs[b * BCAP + pos] = ((uint_t)s << 7) | (uint_t)(d & 127);
  }
}

__global__ __launch_bounds__(256) void count2_k(const int* __restrict__ bcnt, const uint_t* __restrict__ pairs,
                                                int* __restrict__ cnt) {
  __shared__ int c[128];
  int b = blockIdx.x, t = threadIdx.x;
  if (t < 128) c[t] = 0;
  __syncthreads();
  int n = min(bcnt[b], BCAP);
  for (int i = t; i < n; i += 256) atomicAdd(&c[pairs[b * BCAP + i] & 127], 1);
  __syncthreads();
  if (t < 128) {
    int node = b * 128 + t;
    if (node < NN) cnt[node] = c[t];
  }
}

__global__ __launch_bounds__(256) void dinv_k(const int* __restrict__ cnt, float* __restrict__ dinv) {
  int i = blockIdx.x * 256 + threadIdx.x;
  if (i < NN) dinv[i] = rsqrtf((float)(cnt[i] + 1));  // +1 self-loop; always > 0
}

__global__ __launch_bounds__(1024) void scan1(const int* __restrict__ cnt, int* __restrict__ rowstart,
                                              int* __restrict__ blocksum) {
  __shared__ int s[1024];
  int t = threadIdx.x;
  int i = blockIdx.x * 1024 + t;
  int v = (i < NN) ? cnt[i] : 0;
  s[t] = v;
  __syncthreads();
  for (int off = 1; off < 1024; off <<= 1) {
    int add = (t >= off) ? s[t - off] : 0;
    __syncthreads();
    s[t] += add;
    __syncthreads();
  }
  if (i < NN) rowstart[i] = s[t] - v;   // exclusive
  if (t == 1023) blocksum[blockIdx.x] = s[1023];
}

__global__ void scan2(int* blocksum, int nb) {
  if (threadIdx.x == 0 && blockIdx.x == 0) {
    int acc = 0;
    for (int b = 0; b < nb; ++b) { int v = blocksum[b]; blocksum[b] = acc; acc += v; }
  }
}

__global__ __launch_bounds__(1024) void scan3(int* __restrict__ rowstart, const int* __restrict__ blocksum) {
  int i = blockIdx.x * 1024 + threadIdx.x;
  if (i < NN) rowstart[i] += blocksum[blockIdx.x];
}

__global__ __launch_bounds__(256) void fill2_k(const int* __restrict__ bcnt, const uint_t* __restrict__ pairs,
                                               const int* __restrict__ rowstart, int* __restrict__ csr) {
  __shared__ int cur[128];
  int b = blockIdx.x, t = threadIdx.x;
  if (t < 128) cur[t] = 0;
  __syncthreads();
  int n = min(bcnt[b], BCAP);
  for (int i = t; i < n; i += 256) {
    uint_t p = pairs[b * BCAP + i];
    int lo = p & 127;
    int pos = rowstart[b * 128 + lo] + atomicAdd(&cur[lo], 1);
    csr[pos] = (int)(p >> 7);
  }
}

// ---------------- weight prep: transpose + bf16 hi/lo split (k-major rows) ----------------

__global__ __launch_bounds__(256) void wprep_k(const float* __restrict__ Wg1, const float* __restrict__ Wg2,
                                               const float* __restrict__ Wl, const float* __restrict__ Wf,
                                               ushort_t* __restrict__ G1h, ushort_t* __restrict__ G1l,
                                               ushort_t* __restrict__ G2h, ushort_t* __restrict__ G2l,
                                               ushort_t* __restrict__ Lh, ushort_t* __restrict__ Ll,
                                               ushort_t* __restrict__ Fh, ushort_t* __restrict__ Fl) {
  int i = blockIdx.x * 256 + threadIdx.x;   // 0..86015
  float w;
  ushort_t *ph, *pl;
  size_t di;
  if (i < 16384) {           // Wg1 128x128
    int k = i >> 7, n = i & 127;
    w = Wg1[i]; di = (size_t)n * 128 + k; ph = G1h; pl = G1l;
  } else if (i < 32768) {    // Wg2 128x128
    int i2 = i - 16384;
    int k = i2 >> 7, n = i2 & 127;
    w = Wg2[i2]; di = (size_t)n * 128 + k; ph = G2h; pl = G2l;
  } else if (i < 73728) {    // Wl 10 x 64x64
    int i2 = i - 32768;
    int j = i2 >> 12, r = i2 & 4095;
    int k = r >> 6, n = r & 63;
    w = Wl[i2]; di = (size_t)j * 4096 + n * 64 + k; ph = Lh; pl = Ll;
  } else {                   // Wf 192x64
    int i2 = i - 73728;
    int k = i2 >> 6, n = i2 & 63;
    w = Wf[i2]; di = (size_t)n * 192 + k; ph = Fh; pl = Fl;
  }
  ushort_t h = f2bf(w);
  ph[di] = h;
  pl[di] = f2bf(w - bf2f(h));
}

// ---------------- state init: dst = bf16(dinv[node] * src) ----------------

template <int D>
__global__ __launch_bounds__(256) void conv_k(const float* __restrict__ src, const float* __restrict__ dinv,
                                              ushort_t* __restrict__ dst) {
  int i = blockIdx.x * 256 + threadIdx.x;   // one per 8 elems
  if (i >= NN * D / 8) return;
  int node = (i * 8) / D;
  float dv = dinv[node];
  float4 a = *(const float4*)&src[(size_t)i * 8];
  float4 b = *(const float4*)&src[(size_t)i * 8 + 4];
  u16x8 o;
  o[0] = f2bf(a.x * dv); o[1] = f2bf(a.y * dv); o[2] = f2bf(a.z * dv); o[3] = f2bf(a.w * dv);
  o[4] = f2bf(b.x * dv); o[5] = f2bf(b.y * dv); o[6] = f2bf(b.z * dv); o[7] = f2bf(b.w * dv);
  *(u16x8*)&dst[(size_t)i * 8] = o;
}

// ---------------- fused GCN layer: gather-agg (phase A) + MFMA GEMM (phase B) ----------------
// state st holds dinv .* xl (bf16). P = dinv_dst * (sum_{src in N+self} st[src]) = (S xl)_dst.
// out = phaseB(P @ W + b): ACT 0/1 relu; SCALEOUT: store bf16(dinv*v); SPLITOUT: store hi/lo.

template <int K, int DC, int ACT, bool SCALEOUT, bool SPLITOUT>
__global__ __launch_bounds__(256) void fused_k(const uint4* __restrict__ st,
                                               const ushort_t* __restrict__ Wth, const ushort_t* __restrict__ Wtl,
                                               const int* __restrict__ rowstart, const int* __restrict__ cnt,
                                               const int* __restrict__ csr, const float* __restrict__ dinv,
                                               const float* __restrict__ bias,
                                               ushort_t* __restrict__ Ch, ushort_t* __restrict__ Cl) {
  constexpr int LPN = K / 8;          // lanes per node (16B of bf16 each)
  constexpr int ROWS = 256 / LPN;     // 32 (K=64) | 16 (K=128)
  constexpr int NKC = K / 64;
  __shared__ ushort_t Ah[ROWS * K], Al[ROWS * K];
  __shared__ ushort_t Wh[DC * 64], Wl_[DC * 64];
  const int t = threadIdx.x;
  const int row0 = blockIdx.x * ROWS;

  // ---- phase A: gather + prescale + split -> LDS ----
  {
    const int nl = t / LPN, lane = t % LPN;
    const int node = min(row0 + nl, NN - 1);
    float acc[8];
    uint4 sv = st[(size_t)node * LPN + lane];
    {
      uint_t u[4] = {sv.x, sv.y, sv.z, sv.w};
#pragma unroll
      for (int q = 0; q < 4; ++q) {
        acc[2 * q]     = __uint_as_float(u[q] << 16);
        acc[2 * q + 1] = __uint_as_float(u[q] & 0xffff0000u);
      }
    }
    int s = rowstart[node], c = cnt[node];
    for (int j = 0; j < c; ++j) {
      int sn = csr[s + j];
      uint4 v = st[(size_t)sn * LPN + lane];
      uint_t u[4] = {v.x, v.y, v.z, v.w};
#pragma unroll
      for (int q = 0; q < 4; ++q) {
        acc[2 * q]     += __uint_as_float(u[q] << 16);
        acc[2 * q + 1] += __uint_as_float(u[q] & 0xffff0000u);
      }
    }
    float dv = dinv[node];
    u16x8 hv, lv;
#pragma unroll
    for (int q = 0; q < 8; ++q) {
      float p = acc[q] * dv;
      ushort_t h = f2bf(p);
      hv[q] = h;
      lv[q] = f2bf(p - bf2f(h));
    }
    int byt = (nl * (K * 2) + lane * 16) ^ ((nl & 7) << 4);
    *(u16x8*)&Ah[byt >> 1] = hv;
    *(u16x8*)&Al[byt >> 1] = lv;
  }

  // ---- phase B: P @ W via bf16x3 MFMA ----
  const int w = t >> 6, l = t & 63;
  const int lr = l & 15, kh = l >> 4;
  constexpr bool TWO_RG = (ROWS == 32);
  const int rg = TWO_RG ? (w & 1) : 0;
  const int ctb = (TWO_RG ? (w >> 1) : w) * 2;   // 2 col tiles per wave
  f32x4 acc0 = {0.f, 0.f, 0.f, 0.f}, acc1 = {0.f, 0.f, 0.f, 0.f};

  for (int kc = 0; kc < NKC; ++kc) {
    if (kc) __syncthreads();
    for (int idx = t; idx < DC * 8; idx += 256) {
      int n = idx >> 3, kq = idx & 7;
      u16x8 hv = *(const u16x8*)&Wth[(size_t)n * K + kc * 64 + kq * 8];
      u16x8 lv = *(const u16x8*)&Wtl[(size_t)n * K + kc * 64 + kq * 8];
      int byt = (n * 128 + kq * 16) ^ ((n & 7) << 4);
      *(u16x8*)&Wh[byt >> 1] = hv;
      *(u16x8*)&Wl_[byt >> 1] = lv;
    }
    __syncthreads();
#pragma unroll
    for (int kc2 = 0; kc2 < 2; ++kc2) {
      int arow = rg * 16 + lr;
      int ab = (arow * (K * 2) + kc * 128 + kc2 * 64 + kh * 16) ^ ((arow & 7) << 4);
      bf16x8 ah = *(const bf16x8*)&Ah[ab >> 1];
      bf16x8 al = *(const bf16x8*)&Al[ab >> 1];
      {
        int n = ctb * 16 + lr;
        int bb = (n * 128 + kc2 * 64 + kh * 16) ^ ((n & 7) << 4);
        bf16x8 bh = *(const bf16x8*)&Wh[bb >> 1];
        bf16x8 bl = *(const bf16x8*)&Wl_[bb >> 1];
        acc0 = __builtin_amdgcn_mfma_f32_16x16x32_bf16(al, bh, acc0, 0, 0, 0);
        acc0 = __builtin_amdgcn_mfma_f32_16x16x32_bf16(ah, bl, acc0, 0, 0, 0);
        acc0 = __builtin_amdgcn_mfma_f32_16x16x32_bf16(ah, bh, acc0, 0, 0, 0);
      }
      {
        int n = (ctb + 1) * 16 + lr;
        int bb = (n * 128 + kc2 * 64 + kh * 16) ^ ((n & 7) << 4);
        bf16x8 bh = *(const bf16x8*)&Wh[bb >> 1];
        bf16x8 bl = *(const bf16x8*)&Wl_[bb >> 1];
        acc1 = __builtin_amdgcn_mfma_f32_16x16x32_bf16(al, bh, acc1, 0, 0, 0);
        acc1 = __builtin_amdgcn_mfma_f32_16x16x32_bf16(ah, bl, acc1, 0, 0, 0);
        acc1 = __builtin_amdgcn_mfma_f32_16x16x32_bf16(ah, bh, acc1, 0, 0, 0);
      }
    }
  }

  // ---- epilogue: C/D layout col=lane&15, row=(lane>>4)*4+reg ----
  const int col0 = ctb * 16 + lr, col1 = (ctb + 1) * 16 + lr;
  const float b0 = bias[col0], b1 = bias[col1];
#pragma unroll
  for (int r = 0; r < 4; ++r) {
    int grow = row0 + rg * 16 + kh * 4 + r;
    if (grow >= NN) continue;
    float v0 = acc0[r] + b0;
    float v1 = acc1[r] + b1;
    if (ACT == 1) { v0 = fmaxf(v0, 0.f); v1 = fmaxf(v1, 0.f); }
    if constexpr (SPLITOUT) {
      ushort_t h0 = f2bf(v0), h1 = f2bf(v1);
      Ch[(size_t)grow * DC + col0] = h0;
      Cl[(size_t)grow * DC + col0] = f2bf(v0 - bf2f(h0));
      Ch[(size_t)grow * DC + col1] = h1;
      Cl[(size_t)grow * DC + col1] = f2bf(v1 - bf2f(h1));
    } else {
      float dv = SCALEOUT ? dinv[grow] : 1.0f;
      Ch[(size_t)grow * DC + col0] = f2bf(v0 * dv);
      Ch[(size_t)grow * DC + col1] = f2bf(v1 * dv);
    }
  }
}

// ---------------- head: sigmoid([h2 | xl10] @ Wf + bf), A pre-split, MFMA ----------------

__global__ __launch_bounds__(256) void head_k(const ushort_t* __restrict__ A1h, const ushort_t* __restrict__ A1l,
                                              const ushort_t* __restrict__ A2h, const ushort_t* __restrict__ A2l,
                                              const ushort_t* __restrict__ Wfh, const ushort_t* __restrict__ Wfl,
                                              const float* __restrict__ bias, float* __restrict__ out) {
  __shared__ ushort_t Ah[64 * 64], Al[64 * 64];   // per-k-chunk
  __shared__ ushort_t Wh[64 * 64], Wl_[64 * 64];
  const int t = threadIdx.x;
  const int row0 = blockIdx.x * 64;
  const int w = t >> 6, l = t & 63, lr = l & 15, kh = l >> 4;
  f32x4 acc[4];
  const f32x4 zz = {0.f, 0.f, 0.f, 0.f};
#pragma unroll
  for (int ct = 0; ct < 4; ++ct) acc[ct] = zz;

  for (int kc = 0; kc < 3; ++kc) {
    if (kc) __syncthreads();
    // stage A chunk (64 rows x 64 k), pre-split source
    for (int idx = t; idx < 64 * 8; idx += 256) {
      int row = idx >> 3, kq = idx & 7;
      int gr = min(row0 + row, NN - 1);
      u16x8 hv, lv;
      if (kc < 2) {
        hv = *(const u16x8*)&A1h[(size_t)gr * 128 + kc * 64 + kq * 8];
        lv = *(const u16x8*)&A1l[(size_t)gr * 128 + kc * 64 + kq * 8];
      } else {
        hv = *(const u16x8*)&A2h[(size_t)gr * 64 + kq * 8];
        lv = *(const u16x8*)&A2l[(size_t)gr * 64 + kq * 8];
      }
      int byt = (row * 128 + kq * 16) ^ ((row & 7) << 4);
      *(u16x8*)&Ah[byt >> 1] = hv;
      *(u16x8*)&Al[byt >> 1] = lv;
    }
    // stage W chunk
    for (int idx = t; idx < 64 * 8; idx += 256) {
      int n = idx >> 3, kq = idx & 7;
      u16x8 hv = *(const u16x8*)&Wfh[(size_t)n * 192 + kc * 64 + kq * 8];
      u16x8 lv = *(const u16x8*)&Wfl[(size_t)n * 192 + kc * 64 + kq * 8];
      int byt = (n * 128 + kq * 16) ^ ((n & 7) << 4);
      *(u16x8*)&Wh[byt >> 1] = hv;
      *(u16x8*)&Wl_[byt >> 1] = lv;
    }
    __syncthreads();
#pragma unroll
    for (int kc2 = 0; kc2 < 2; ++kc2) {
      int arow = w * 16 + lr;
      int ab = (arow * 128 + kc2 * 64 + kh * 16) ^ ((arow & 7) << 4);
      bf16x8 ah = *(const bf16x8*)&Ah[ab >> 1];
      bf16x8 al = *(const bf16x8*)&Al[ab >> 1];
#pragma unroll
      for (int ct = 0; ct < 4; ++ct) {
        int n = ct * 16 + lr;
        int bb = (n * 128 + kc2 * 64 + kh * 16) ^ ((n & 7) << 4);
        bf16x8 bh = *(const bf16x8*)&Wh[bb >> 1];
        bf16x8 bl = *(const bf16x8*)&Wl_[bb >> 1];
        acc[ct] = __builtin_amdgcn_mfma_f32_16x16x32_bf16(al, bh, acc[ct], 0, 0, 0);
        acc[ct] = __builtin_amdgcn_mfma_f32_16x16x32_bf16(ah, bl, acc[ct], 0, 0, 0);
        acc[ct] = __builtin_amdgcn_mfma_f32_16x16x32_bf16(ah, bh, acc[ct], 0, 0, 0);
      }
    }
  }
#pragma unroll
  for (int ct = 0; ct < 4; ++ct) {
    int col = ct * 16 + lr;
    float b = bias[col];
#pragma unroll
    for (int r = 0; r < 4; ++r) {
      int grow = row0 + w * 16 + kh * 4 + r;
      if (grow < NN) {
        float v = acc[ct][r] + b;
        out[(size_t)grow * 64 + col] = 1.0f / (1.0f + __expf(-v));
      }
    }
  }
}

// ---------------- launch ----------------

extern "C" void kernel_launch(void* const* d_in, const int* in_sizes, int n_in,
                              void* d_out, int out_size, void* d_ws, size_t ws_size,
                              hipStream_t stream) {
  const float* x  = (const float*)d_in[0];
  const float* y  = (const float*)d_in[1];
  const int* ei   = (const int*)d_in[2];
  const float* Wg1 = (const float*)d_in[3];
  const float* bg1 = (const float*)d_in[4];
  const float* Wg2 = (const float*)d_in[5];
  const float* bg2 = (const float*)d_in[6];
  const float* Wl  = (const float*)d_in[7];
  const float* bl  = (const float*)d_in[8];
  const float* Wf  = (const float*)d_in[9];
  const float* bf  = (const float*)d_in[10];
  float* out = (float*)d_out;

  char* ws = (char*)d_ws;
  size_t off = 0;
  auto alloc = [&](size_t bytes) { void* p = ws + off; off += (bytes + 511) & ~(size_t)511; return p; };
  int* cnt      = (int*)alloc((size_t)NN * 4);
  int* rowstart = (int*)alloc((size_t)NN * 4);
  int* blocksum = (int*)alloc(512);
  float* dinv   = (float*)alloc((size_t)NN * 4);
  int* csr      = (int*)alloc((size_t)NE * 4);
  int* bcnt     = (int*)alloc((size_t)NB * 4);
  uint_t* pairs = (uint_t*)alloc((size_t)NB * BCAP * 4);
  ushort_t* xs  = (ushort_t*)alloc((size_t)NN * 128 * 2);  // dinv.*x bf16; label ping/pong later
  ushort_t* ys  = (ushort_t*)alloc((size_t)NN * 64 * 2);   // dinv.*y bf16
  ushort_t* hs  = (ushort_t*)alloc((size_t)NN * 128 * 2);  // dinv.*h bf16; xl10 hi/lo later
  ushort_t* h2h = (ushort_t*)alloc((size_t)NN * 128 * 2);  // h2 split hi
  ushort_t* h2l = (ushort_t*)alloc((size_t)NN * 128 * 2);  // h2 split lo
  ushort_t* G1h = (ushort_t*)alloc(128 * 128 * 2);
  ushort_t* G1l = (ushort_t*)alloc(128 * 128 * 2);
  ushort_t* G2h = (ushort_t*)alloc(128 * 128 * 2);
  ushort_t* G2l = (ushort_t*)alloc(128 * 128 * 2);
  ushort_t* Lh  = (ushort_t*)alloc(10 * 64 * 64 * 2);
  ushort_t* Ll  = (ushort_t*)alloc(10 * 64 * 64 * 2);
  ushort_t* Fh  = (ushort_t*)alloc(192 * 64 * 2);
  ushort_t* Fl  = (ushort_t*)alloc(192 * 64 * 2);
  // aliases (dead-buffer reuse)
  ushort_t* xlA   = xs;                        // label ping (xs dead after feature conv1)
  ushort_t* xlB   = xs + (size_t)NN * 64;      // label pong (second half of xs)
  ushort_t* xl10h = hs;                        // xl10 split (hs dead after conv2)
  ushort_t* xl10l = hs + (size_t)NN * 64;

  const int* esrc = ei;
  const int* edst = ei + NE;

  wprep_k<<<336, 256, 0, stream>>>(Wg1, Wg2, Wl, Wf, G1h, G1l, G2h, G2l, Lh, Ll, Fh, Fl);
  hipMemsetAsync(bcnt, 0, (size_t)NB * 4, stream);
  bucketA_k<<<BKBLK, 512, 0, stream>>>(esrc, edst, bcnt, pairs);
  count2_k<<<NB, 256, 0, stream>>>(bcnt, pairs, cnt);
  dinv_k<<<(NN + 255) / 256, 256, 0, stream>>>(cnt, dinv);
  scan1<<<98, 1024, 0, stream>>>(cnt, rowstart, blocksum);
  scan2<<<1, 1, 0, stream>>>(blocksum, 98);
  scan3<<<98, 1024, 0, stream>>>(rowstart, blocksum);
  fill2_k<<<NB, 256, 0, stream>>>(bcnt, pairs, rowstart, csr);

  conv_k<128><<<NN * 16 / 256, 256, 0, stream>>>(x, dinv, xs);
  conv_k<64><<<NN * 8 / 256, 256, 0, stream>>>(y, dinv, ys);

  // feature branch: conv1 (relu, scaled state), conv2 (no relu, split out for head)
  fused_k<128, 128, 1, true, false><<<NN / 16, 256, 0, stream>>>(
      (const uint4*)xs, G1h, G1l, rowstart, cnt, csr, dinv, bg1, hs, nullptr);
  fused_k<128, 128, 0, false, true><<<NN / 16, 256, 0, stream>>>(
      (const uint4*)hs, G2h, G2l, rowstart, cnt, csr, dinv, bg2, h2h, h2l);

  // label branch: 10 layers; j<9 relu+scaled state, j=9 split out for head
  const ushort_t* in = ys;
  for (int j = 0; j < 9; ++j) {
    ushort_t* nxt = (j & 1) ? xlB : xlA;
    fused_k<64, 64, 1, true, false><<<NN / 32, 256, 0, stream>>>(
        (const uint4*)in, Lh + (size_t)j * 4096, Ll + (size_t)j * 4096,
        rowstart, cnt, csr, dinv, bl + (size_t)j * 64, nxt, nullptr);
    in = nxt;
  }
  fused_k<64, 64, 0, false, true><<<NN / 32, 256, 0, stream>>>(
      (const uint4*)in, Lh + (size_t)9 * 4096, Ll + (size_t)9 * 4096,
      rowstart, cnt, csr, dinv, bl + (size_t)9 * 64, xl10h, xl10l);

  // head
  head_k<<<(NN + 63) / 64, 256, 0, stream>>>(h2h, h2l, xl10h, xl10l, Fh, Fl, bf, out);
}

// Round 6
// 821.955 us; speedup vs baseline: 1.1938x; 1.1938x over previous
//
#include <hip/hip_runtime.h>
#include <math.h>

#define NN 100000
#define NE 1600000
#define NB 782      // dst buckets of 128 nodes
#define BCAP 3072   // bucket capacity (mean ~2046, 22 sigma safe)
#define BKBLK 128   // blocks in bucket build
#define BKCHUNK (NE / BKBLK)  // 12500 edges per block
#define DBINS 64    // degree bins for counting sort

typedef unsigned short ushort_t;
typedef unsigned int uint_t;
typedef __attribute__((ext_vector_type(8))) short bf16x8;
typedef __attribute__((ext_vector_type(8))) unsigned short u16x8;
typedef __attribute__((ext_vector_type(4))) float f32x4;

__device__ __forceinline__ ushort_t f2bf(float f) {
  uint_t u = __float_as_uint(f);
  u = (u + 0x7fffu + ((u >> 16) & 1u)) >> 16;   // round-to-nearest-even
  return (ushort_t)u;
}
__device__ __forceinline__ float bf2f(ushort_t h) {
  return __uint_as_float((uint_t)h << 16);
}

// ---------------- setup: bucketed CSR build (histogram + reserve + write) ----------------

__global__ __launch_bounds__(512) void bucketA_k(const int* __restrict__ src, const int* __restrict__ dst,
                                                 int* __restrict__ bcnt, uint_t* __restrict__ pairs) {
  __shared__ int h[NB];
  const int t = threadIdx.x;
  const int e0 = blockIdx.x * BKCHUNK;
  for (int b = t; b < NB; b += 512) h[b] = 0;
  __syncthreads();
  for (int i = t; i < BKCHUNK; i += 512) atomicAdd(&h[dst[e0 + i] >> 7], 1);
  __syncthreads();
  for (int b = t; b < NB; b += 512) h[b] = atomicAdd(&bcnt[b], h[b]);
  __syncthreads();
  for (int i = t; i < BKCHUNK; i += 512) {
    int s = src[e0 + i], d = dst[e0 + i];
    int b = d >> 7;
    int pos = atomicAdd(&h[b], 1);
    if (pos < BCAP) pairs[b * BCAP + pos] = ((uint_t)s << 7) | (uint_t)(d & 127);
  }
}

__global__ __launch_bounds__(256) void count2_k(const int* __restrict__ bcnt, const uint_t* __restrict__ pairs,
                                                int* __restrict__ cnt) {
  __shared__ int c[128];
  int b = blockIdx.x, t = threadIdx.x;
  if (t < 128) c[t] = 0;
  __syncthreads();
  int n = min(bcnt[b], BCAP);
  for (int i = t; i < n; i += 256) atomicAdd(&c[pairs[b * BCAP + i] & 127], 1);
  __syncthreads();
  if (t < 128) {
    int node = b * 128 + t;
    if (node < NN) cnt[node] = c[t];
  }
}

__global__ __launch_bounds__(256) void dinv_k(const int* __restrict__ cnt, float* __restrict__ dinv) {
  int i = blockIdx.x * 256 + threadIdx.x;
  if (i < NN) dinv[i] = rsqrtf((float)(cnt[i] + 1));  // +1 self-loop; always > 0
}

__global__ __launch_bounds__(1024) void scan1(const int* __restrict__ cnt, int* __restrict__ rowstart,
                                              int* __restrict__ blocksum) {
  __shared__ int s[1024];
  int t = threadIdx.x;
  int i = blockIdx.x * 1024 + t;
  int v = (i < NN) ? cnt[i] : 0;
  s[t] = v;
  __syncthreads();
  for (int off = 1; off < 1024; off <<= 1) {
    int add = (t >= off) ? s[t - off] : 0;
    __syncthreads();
    s[t] += add;
    __syncthreads();
  }
  if (i < NN) rowstart[i] = s[t] - v;   // exclusive
  if (t == 1023) blocksum[blockIdx.x] = s[1023];
}

__global__ void scan2(int* blocksum, int nb) {
  if (threadIdx.x == 0 && blockIdx.x == 0) {
    int acc = 0;
    for (int b = 0; b < nb; ++b) { int v = blocksum[b]; blocksum[b] = acc; acc += v; }
  }
}

__global__ __launch_bounds__(1024) void scan3(int* __restrict__ rowstart, const int* __restrict__ blocksum) {
  int i = blockIdx.x * 1024 + threadIdx.x;
  if (i < NN) rowstart[i] += blocksum[blockIdx.x];
}

__global__ __launch_bounds__(256) void fill2_k(const int* __restrict__ bcnt, const uint_t* __restrict__ pairs,
                                               const int* __restrict__ rowstart, int* __restrict__ csr) {
  __shared__ int cur[128];
  int b = blockIdx.x, t = threadIdx.x;
  if (t < 128) cur[t] = 0;
  __syncthreads();
  int n = min(bcnt[b], BCAP);
  for (int i = t; i < n; i += 256) {
    uint_t p = pairs[b * BCAP + i];
    int lo = p & 127;
    int pos = rowstart[b * 128 + lo] + atomicAdd(&cur[lo], 1);
    csr[pos] = (int)(p >> 7);
  }
}

// ---------------- degree counting sort: perm[] groups equal-degree nodes ----------------

__global__ __launch_bounds__(256) void dhist_k(const int* __restrict__ cnt, int* __restrict__ dbin) {
  __shared__ int h[DBINS];
  int t = threadIdx.x;
  if (t < DBINS) h[t] = 0;
  __syncthreads();
  int i = blockIdx.x * 256 + t;
  if (i < NN) atomicAdd(&h[min(cnt[i], DBINS - 1)], 1);
  __syncthreads();
  if (t < DBINS && h[t]) atomicAdd(&dbin[t], h[t]);
}

__global__ void dscan_k(const int* __restrict__ dbin, int* __restrict__ dcur) {
  if (threadIdx.x == 0 && blockIdx.x == 0) {
    int acc = 0;
    for (int b = 0; b < DBINS; ++b) { dcur[b] = acc; acc += dbin[b]; }
  }
}

__global__ __launch_bounds__(256) void dplace_k(const int* __restrict__ cnt, int* __restrict__ dcur,
                                                int* __restrict__ perm) {
  __shared__ int h[DBINS];
  __shared__ int lbase[DBINS];
  int t = threadIdx.x;
  if (t < DBINS) h[t] = 0;
  __syncthreads();
  int i = blockIdx.x * 256 + t;
  int bin = 0, lrank = 0;
  if (i < NN) { bin = min(cnt[i], DBINS - 1); lrank = atomicAdd(&h[bin], 1); }
  __syncthreads();
  if (t < DBINS) lbase[t] = h[t] ? atomicAdd(&dcur[t], h[t]) : 0;
  __syncthreads();
  if (i < NN) perm[lbase[bin] + lrank] = i;
}

// ---------------- weight prep: transpose + bf16 hi/lo split (k-major rows) ----------------

__global__ __launch_bounds__(256) void wprep_k(const float* __restrict__ Wg1, const float* __restrict__ Wg2,
                                               const float* __restrict__ Wl, const float* __restrict__ Wf,
                                               ushort_t* __restrict__ G1h, ushort_t* __restrict__ G1l,
                                               ushort_t* __restrict__ G2h, ushort_t* __restrict__ G2l,
                                               ushort_t* __restrict__ Lh, ushort_t* __restrict__ Ll,
                                               ushort_t* __restrict__ Fh, ushort_t* __restrict__ Fl) {
  int i = blockIdx.x * 256 + threadIdx.x;   // 0..86015
  float w;
  ushort_t *ph, *pl;
  size_t di;
  if (i < 16384) {           // Wg1 128x128
    int k = i >> 7, n = i & 127;
    w = Wg1[i]; di = (size_t)n * 128 + k; ph = G1h; pl = G1l;
  } else if (i < 32768) {    // Wg2 128x128
    int i2 = i - 16384;
    int k = i2 >> 7, n = i2 & 127;
    w = Wg2[i2]; di = (size_t)n * 128 + k; ph = G2h; pl = G2l;
  } else if (i < 73728) {    // Wl 10 x 64x64
    int i2 = i - 32768;
    int j = i2 >> 12, r = i2 & 4095;
    int k = r >> 6, n = r & 63;
    w = Wl[i2]; di = (size_t)j * 4096 + n * 64 + k; ph = Lh; pl = Ll;
  } else {                   // Wf 192x64
    int i2 = i - 73728;
    int k = i2 >> 6, n = i2 & 63;
    w = Wf[i2]; di = (size_t)n * 192 + k; ph = Fh; pl = Fl;
  }
  ushort_t h = f2bf(w);
  ph[di] = h;
  pl[di] = f2bf(w - bf2f(h));
}

// ---------------- MFMA GEMM (bf16x3 split ~ f32 accuracy) ----------------
// C[i,n] = bf16( dinv[i] * sum_k A[i,k] W[k,n] ).  64 rows/block, 4 waves.

template <int K, int DC>
__global__ __launch_bounds__(256) void mgemm_k(const float* __restrict__ A,
                                               const ushort_t* __restrict__ Wth, const ushort_t* __restrict__ Wtl,
                                               const float* __restrict__ dinv, ushort_t* __restrict__ C) {
  constexpr int NCH = K / 64;
  __shared__ ushort_t Ah[64 * 64], Al[64 * 64];
  __shared__ ushort_t Wh[DC * 64], Wl_[DC * 64];
  const int t = threadIdx.x;
  const int row0 = blockIdx.x * 64;
  const int w = t >> 6, l = t & 63;
  const int lr = l & 15, kh = l >> 4;

  f32x4 acc[DC / 16];
  const f32x4 zz = {0.f, 0.f, 0.f, 0.f};
#pragma unroll
  for (int ct = 0; ct < DC / 16; ++ct) acc[ct] = zz;

  for (int kc = 0; kc < NCH; ++kc) {
    if (kc) __syncthreads();
#pragma unroll
    for (int it = 0; it < 4; ++it) {
      int idx = t + it * 256;
      int row = idx >> 4, kq = idx & 15;
      int gr = min(row0 + row, NN - 1);
      float4 a = *(const float4*)&A[(size_t)gr * K + kc * 64 + kq * 4];
      ushort4 h, lo;
      h.x = f2bf(a.x); lo.x = f2bf(a.x - bf2f(h.x));
      h.y = f2bf(a.y); lo.y = f2bf(a.y - bf2f(h.y));
      h.z = f2bf(a.z); lo.z = f2bf(a.z - bf2f(h.z));
      h.w = f2bf(a.w); lo.w = f2bf(a.w - bf2f(h.w));
      int byt = (row * 128 + kq * 8) ^ ((row & 7) << 4);
      *(ushort4*)&Ah[byt >> 1] = h;
      *(ushort4*)&Al[byt >> 1] = lo;
    }
    for (int idx = t; idx < DC * 8; idx += 256) {
      int n = idx >> 3, kq = idx & 7;
      u16x8 hv = *(const u16x8*)&Wth[(size_t)n * K + kc * 64 + kq * 8];
      u16x8 lv = *(const u16x8*)&Wtl[(size_t)n * K + kc * 64 + kq * 8];
      int byt = (n * 128 + kq * 16) ^ ((n & 7) << 4);
      *(u16x8*)&Wh[byt >> 1] = hv;
      *(u16x8*)&Wl_[byt >> 1] = lv;
    }
    __syncthreads();
#pragma unroll
    for (int kc2 = 0; kc2 < 2; ++kc2) {
      int arow = w * 16 + lr;
      int ab = (arow * 128 + kc2 * 64 + kh * 16) ^ ((arow & 7) << 4);
      bf16x8 ah = *(const bf16x8*)&Ah[ab >> 1];
      bf16x8 al = *(const bf16x8*)&Al[ab >> 1];
#pragma unroll
      for (int ct = 0; ct < DC / 16; ++ct) {
        int n = ct * 16 + lr;
        int bb = (n * 128 + kc2 * 64 + kh * 16) ^ ((n & 7) << 4);
        bf16x8 bh = *(const bf16x8*)&Wh[bb >> 1];
        bf16x8 bl = *(const bf16x8*)&Wl_[bb >> 1];
        acc[ct] = __builtin_amdgcn_mfma_f32_16x16x32_bf16(al, bh, acc[ct], 0, 0, 0);
        acc[ct] = __builtin_amdgcn_mfma_f32_16x16x32_bf16(ah, bl, acc[ct], 0, 0, 0);
        acc[ct] = __builtin_amdgcn_mfma_f32_16x16x32_bf16(ah, bh, acc[ct], 0, 0, 0);
      }
    }
  }
  float dv[4];
#pragma unroll
  for (int r = 0; r < 4; ++r) {
    int grow = row0 + w * 16 + kh * 4 + r;
    dv[r] = (grow < NN) ? dinv[grow] : 0.0f;
  }
#pragma unroll
  for (int ct = 0; ct < DC / 16; ++ct) {
    int col = ct * 16 + lr;
#pragma unroll
    for (int r = 0; r < 4; ++r) {
      int grow = row0 + w * 16 + kh * 4 + r;
      if (grow < NN) C[(size_t)grow * DC + col] = f2bf(acc[ct][r] * dv[r]);
    }
  }
}

// ---------------- aggregation (bf16 rows, f32 accum/out), degree-sorted via perm ----------------

template <int D, int ACT>
__global__ __launch_bounds__(256) void agg_k(const uint4* __restrict__ t, const int* __restrict__ perm,
                                             const int* __restrict__ rowstart, const int* __restrict__ cnt,
                                             const int* __restrict__ csr, const float* __restrict__ dinv,
                                             const float* __restrict__ bias, float* __restrict__ out) {
  constexpr int LPN = D / 8;
  int slot = blockIdx.x * (256 / LPN) + threadIdx.x / LPN;
  int lane = threadIdx.x % LPN;
  if (slot >= NN) return;
  int node = perm[slot];

  float acc[8];
  uint4 sv = t[(size_t)node * LPN + lane];
  {
    uint_t u[4] = {sv.x, sv.y, sv.z, sv.w};
#pragma unroll
    for (int q = 0; q < 4; ++q) {
      acc[2 * q]     = __uint_as_float(u[q] << 16);
      acc[2 * q + 1] = __uint_as_float(u[q] & 0xffff0000u);
    }
  }
  int s = rowstart[node], c = cnt[node];
  int j = 0;
  for (; j + 4 <= c; j += 4) {
    int i0 = csr[s + j], i1 = csr[s + j + 1], i2 = csr[s + j + 2], i3 = csr[s + j + 3];
    uint4 v0 = t[(size_t)i0 * LPN + lane];
    uint4 v1 = t[(size_t)i1 * LPN + lane];
    uint4 v2 = t[(size_t)i2 * LPN + lane];
    uint4 v3 = t[(size_t)i3 * LPN + lane];
    uint_t u0[4] = {v0.x, v0.y, v0.z, v0.w};
    uint_t u1[4] = {v1.x, v1.y, v1.z, v1.w};
    uint_t u2[4] = {v2.x, v2.y, v2.z, v2.w};
    uint_t u3[4] = {v3.x, v3.y, v3.z, v3.w};
#pragma unroll
    for (int q = 0; q < 4; ++q) {
      acc[2 * q]     += __uint_as_float(u0[q] << 16);
      acc[2 * q + 1] += __uint_as_float(u0[q] & 0xffff0000u);
    }
#pragma unroll
    for (int q = 0; q < 4; ++q) {
      acc[2 * q]     += __uint_as_float(u1[q] << 16);
      acc[2 * q + 1] += __uint_as_float(u1[q] & 0xffff0000u);
    }
#pragma unroll
    for (int q = 0; q < 4; ++q) {
      acc[2 * q]     += __uint_as_float(u2[q] << 16);
      acc[2 * q + 1] += __uint_as_float(u2[q] & 0xffff0000u);
    }
#pragma unroll
    for (int q = 0; q < 4; ++q) {
      acc[2 * q]     += __uint_as_float(u3[q] << 16);
      acc[2 * q + 1] += __uint_as_float(u3[q] & 0xffff0000u);
    }
  }
  for (; j < c; ++j) {
    int sn = csr[s + j];
    uint4 v = t[(size_t)sn * LPN + lane];
    uint_t u[4] = {v.x, v.y, v.z, v.w};
#pragma unroll
    for (int q = 0; q < 4; ++q) {
      acc[2 * q]     += __uint_as_float(u[q] << 16);
      acc[2 * q + 1] += __uint_as_float(u[q] & 0xffff0000u);
    }
  }
  float dv = dinv[node];
  float o[8];
#pragma unroll
  for (int q = 0; q < 8; ++q) {
    o[q] = acc[q] * dv + bias[lane * 8 + q];
    if (ACT == 1) o[q] = fmaxf(o[q], 0.0f);
  }
  size_t base = (size_t)node * D + lane * 8;
  float4 o0 = {o[0], o[1], o[2], o[3]};
  float4 o1 = {o[4], o[5], o[6], o[7]};
  *(float4*)&out[base] = o0;
  *(float4*)&out[base + 4] = o1;
}

// ---------------- head: sigmoid([h2 | xl10] @ Wf + bf) via bf16x3 MFMA ----------------

__global__ __launch_bounds__(256) void head_k(const float* __restrict__ A1, const float* __restrict__ A2,
                                              const ushort_t* __restrict__ Wfh, const ushort_t* __restrict__ Wfl,
                                              const float* __restrict__ bias, float* __restrict__ out) {
  __shared__ ushort_t Ah[64 * 64], Al[64 * 64];   // per-k-chunk
  __shared__ ushort_t Wh[64 * 64], Wl_[64 * 64];
  const int t = threadIdx.x;
  const int row0 = blockIdx.x * 64;
  const int w = t >> 6, l = t & 63, lr = l & 15, kh = l >> 4;
  f32x4 acc[4];
  const f32x4 zz = {0.f, 0.f, 0.f, 0.f};
#pragma unroll
  for (int ct = 0; ct < 4; ++ct) acc[ct] = zz;

  for (int kc = 0; kc < 3; ++kc) {
    if (kc) __syncthreads();
    // stage A chunk (64 rows x 64 k) from f32, split hi/lo
#pragma unroll
    for (int it = 0; it < 4; ++it) {
      int idx = t + it * 256;
      int row = idx >> 4, kq = idx & 15;
      int gr = min(row0 + row, NN - 1);
      float4 a = (kc < 2) ? *(const float4*)&A1[(size_t)gr * 128 + kc * 64 + kq * 4]
                          : *(const float4*)&A2[(size_t)gr * 64 + kq * 4];
      ushort4 h, lo;
      h.x = f2bf(a.x); lo.x = f2bf(a.x - bf2f(h.x));
      h.y = f2bf(a.y); lo.y = f2bf(a.y - bf2f(h.y));
      h.z = f2bf(a.z); lo.z = f2bf(a.z - bf2f(h.z));
      h.w = f2bf(a.w); lo.w = f2bf(a.w - bf2f(h.w));
      int byt = (row * 128 + kq * 8) ^ ((row & 7) << 4);
      *(ushort4*)&Ah[byt >> 1] = h;
      *(ushort4*)&Al[byt >> 1] = lo;
    }
    // stage W chunk (pre-split, k-major rows of 192)
    for (int idx = t; idx < 64 * 8; idx += 256) {
      int n = idx >> 3, kq = idx & 7;
      u16x8 hv = *(const u16x8*)&Wfh[(size_t)n * 192 + kc * 64 + kq * 8];
      u16x8 lv = *(const u16x8*)&Wfl[(size_t)n * 192 + kc * 64 + kq * 8];
      int byt = (n * 128 + kq * 16) ^ ((n & 7) << 4);
      *(u16x8*)&Wh[byt >> 1] = hv;
      *(u16x8*)&Wl_[byt >> 1] = lv;
    }
    __syncthreads();
#pragma unroll
    for (int kc2 = 0; kc2 < 2; ++kc2) {
      int arow = w * 16 + lr;
      int ab = (arow * 128 + kc2 * 64 + kh * 16) ^ ((arow & 7) << 4);
      bf16x8 ah = *(const bf16x8*)&Ah[ab >> 1];
      bf16x8 al = *(const bf16x8*)&Al[ab >> 1];
#pragma unroll
      for (int ct = 0; ct < 4; ++ct) {
        int n = ct * 16 + lr;
        int bb = (n * 128 + kc2 * 64 + kh * 16) ^ ((n & 7) << 4);
        bf16x8 bh = *(const bf16x8*)&Wh[bb >> 1];
        bf16x8 bl = *(const bf16x8*)&Wl_[bb >> 1];
        acc[ct] = __builtin_amdgcn_mfma_f32_16x16x32_bf16(al, bh, acc[ct], 0, 0, 0);
        acc[ct] = __builtin_amdgcn_mfma_f32_16x16x32_bf16(ah, bl, acc[ct], 0, 0, 0);
        acc[ct] = __builtin_amdgcn_mfma_f32_16x16x32_bf16(ah, bh, acc[ct], 0, 0, 0);
      }
    }
  }
#pragma unroll
  for (int ct = 0; ct < 4; ++ct) {
    int col = ct * 16 + lr;
    float b = bias[col];
#pragma unroll
    for (int r = 0; r < 4; ++r) {
      int grow = row0 + w * 16 + kh * 4 + r;
      if (grow < NN) {
        float v = acc[ct][r] + b;
        out[(size_t)grow * 64 + col] = 1.0f / (1.0f + __expf(-v));
      }
    }
  }
}

// ---------------- launch ----------------

extern "C" void kernel_launch(void* const* d_in, const int* in_sizes, int n_in,
                              void* d_out, int out_size, void* d_ws, size_t ws_size,
                              hipStream_t stream) {
  const float* x  = (const float*)d_in[0];
  const float* y  = (const float*)d_in[1];
  const int* ei   = (const int*)d_in[2];
  const float* Wg1 = (const float*)d_in[3];
  const float* bg1 = (const float*)d_in[4];
  const float* Wg2 = (const float*)d_in[5];
  const float* bg2 = (const float*)d_in[6];
  const float* Wl  = (const float*)d_in[7];
  const float* bl  = (const float*)d_in[8];
  const float* Wf  = (const float*)d_in[9];
  const float* bf  = (const float*)d_in[10];
  float* out = (float*)d_out;

  char* ws = (char*)d_ws;
  size_t off = 0;
  auto alloc = [&](size_t bytes) { void* p = ws + off; off += (bytes + 511) & ~(size_t)511; return p; };
  int* cnt      = (int*)alloc((size_t)NN * 4);
  int* rowstart = (int*)alloc((size_t)NN * 4);
  int* blocksum = (int*)alloc(512);
  float* dinv   = (float*)alloc((size_t)NN * 4);
  int* csr      = (int*)alloc((size_t)NE * 4);
  int* bcnt     = (int*)alloc((size_t)NB * 4);
  uint_t* pairs = (uint_t*)alloc((size_t)NB * BCAP * 4);
  int* perm     = (int*)alloc((size_t)NN * 4);
  int* dbin     = (int*)alloc(DBINS * 4);
  int* dcur     = (int*)alloc(DBINS * 4);
  ushort_t* Tb  = (ushort_t*)alloc((size_t)NN * 128 * 2);  // bf16 GEMM->agg (feature); XL0 alias later
  float* H      = (float*)alloc((size_t)NN * 128 * 4);     // f32 agg output / GEMM input
  ushort_t* Ub  = (ushort_t*)alloc((size_t)NN * 64 * 2);   // bf16 GEMM->agg (label)
  float* XL1    = (float*)alloc((size_t)NN * 64 * 4);
  ushort_t* G1h = (ushort_t*)alloc(128 * 128 * 2);
  ushort_t* G1l = (ushort_t*)alloc(128 * 128 * 2);
  ushort_t* G2h = (ushort_t*)alloc(128 * 128 * 2);
  ushort_t* G2l = (ushort_t*)alloc(128 * 128 * 2);
  ushort_t* Lh  = (ushort_t*)alloc(10 * 64 * 64 * 2);
  ushort_t* Ll  = (ushort_t*)alloc(10 * 64 * 64 * 2);
  ushort_t* Fh  = (ushort_t*)alloc(192 * 64 * 2);
  ushort_t* Fl  = (ushort_t*)alloc(192 * 64 * 2);
  float* XL0 = (float*)Tb;   // 25.6MB, exactly NN*64*4

  const int* esrc = ei;
  const int* edst = ei + NE;

  wprep_k<<<336, 256, 0, stream>>>(Wg1, Wg2, Wl, Wf, G1h, G1l, G2h, G2l, Lh, Ll, Fh, Fl);
  hipMemsetAsync(bcnt, 0, (size_t)NB * 4, stream);
  hipMemsetAsync(dbin, 0, DBINS * 4, stream);
  bucketA_k<<<BKBLK, 512, 0, stream>>>(esrc, edst, bcnt, pairs);
  count2_k<<<NB, 256, 0, stream>>>(bcnt, pairs, cnt);
  dinv_k<<<(NN + 255) / 256, 256, 0, stream>>>(cnt, dinv);
  scan1<<<98, 1024, 0, stream>>>(cnt, rowstart, blocksum);
  scan2<<<1, 1, 0, stream>>>(blocksum, 98);
  scan3<<<98, 1024, 0, stream>>>(rowstart, blocksum);
  fill2_k<<<NB, 256, 0, stream>>>(bcnt, pairs, rowstart, csr);
  dhist_k<<<(NN + 255) / 256, 256, 0, stream>>>(cnt, dbin);
  dscan_k<<<1, 64, 0, stream>>>(dbin, dcur);
  dplace_k<<<(NN + 255) / 256, 256, 0, stream>>>(cnt, dcur, perm);

  // feature branch
  mgemm_k<128, 128><<<(NN + 63) / 64, 256, 0, stream>>>(x, G1h, G1l, dinv, Tb);
  agg_k<128, 1><<<NN / 16, 256, 0, stream>>>((const uint4*)Tb, perm, rowstart, cnt, csr, dinv, bg1, H);
  mgemm_k<128, 128><<<(NN + 63) / 64, 256, 0, stream>>>(H, G2h, G2l, dinv, Tb);
  agg_k<128, 0><<<NN / 16, 256, 0, stream>>>((const uint4*)Tb, perm, rowstart, cnt, csr, dinv, bg2, H);

  // label branch: 10 layers, relu except last
  const float* xl = y;
  for (int j = 0; j < 10; ++j) {
    mgemm_k<64, 64><<<(NN + 63) / 64, 256, 0, stream>>>(xl, Lh + (size_t)j * 4096, Ll + (size_t)j * 4096, dinv, Ub);
    float* nxt = (j & 1) ? XL1 : XL0;
    if (j < 9)
      agg_k<64, 1><<<NN / 32, 256, 0, stream>>>((const uint4*)Ub, perm, rowstart, cnt, csr, dinv, bl + (size_t)j * 64, nxt);
    else
      agg_k<64, 0><<<NN / 32, 256, 0, stream>>>((const uint4*)Ub, perm, rowstart, cnt, csr, dinv, bl + (size_t)j * 64, nxt);
    xl = nxt;
  }

  // head: sigmoid([h2 | xl10] @ Wf + bf), xl ended in XL1 (j=9 odd)
  head_k<<<(NN + 63) / 64, 256, 0, stream>>>(H, XL1, Fh, Fl, bf, out);
}

// Round 7
// 690.920 us; speedup vs baseline: 1.4202x; 1.1897x over previous
//
#include <hip/hip_runtime.h>
#include <math.h>

#define NN 100000
#define NE 1600000
#define NB 782      // dst buckets of 128 nodes
#define BCAP 3072   // bucket capacity (mean ~2046, 22 sigma safe)
#define BKBLK 128   // blocks in bucket build
#define BKCHUNK (NE / BKBLK)  // 12500 edges per block
#define DBINS 64    // degree bins for counting sort

typedef unsigned short ushort_t;
typedef unsigned int uint_t;
typedef __attribute__((ext_vector_type(8))) short bf16x8;
typedef __attribute__((ext_vector_type(8))) unsigned short u16x8;
typedef __attribute__((ext_vector_type(4))) float f32x4;

__device__ __forceinline__ ushort_t f2bf(float f) {
  uint_t u = __float_as_uint(f);
  u = (u + 0x7fffu + ((u >> 16) & 1u)) >> 16;   // round-to-nearest-even
  return (ushort_t)u;
}
__device__ __forceinline__ float bf2f(ushort_t h) {
  return __uint_as_float((uint_t)h << 16);
}

// ---------------- setup: bucketed CSR build (histogram + reserve + write) ----------------

__global__ __launch_bounds__(512) void bucketA_k(const int* __restrict__ src, const int* __restrict__ dst,
                                                 int* __restrict__ bcnt, uint_t* __restrict__ pairs) {
  __shared__ int h[NB];
  const int t = threadIdx.x;
  const int e0 = blockIdx.x * BKCHUNK;
  for (int b = t; b < NB; b += 512) h[b] = 0;
  __syncthreads();
  for (int i = t; i < BKCHUNK; i += 512) atomicAdd(&h[dst[e0 + i] >> 7], 1);
  __syncthreads();
  for (int b = t; b < NB; b += 512) h[b] = atomicAdd(&bcnt[b], h[b]);
  __syncthreads();
  for (int i = t; i < BKCHUNK; i += 512) {
    int s = src[e0 + i], d = dst[e0 + i];
    int b = d >> 7;
    int pos = atomicAdd(&h[b], 1);
    if (pos < BCAP) pairs[b * BCAP + pos] = ((uint_t)s << 7) | (uint_t)(d & 127);
  }
}

__global__ __launch_bounds__(256) void count2_k(const int* __restrict__ bcnt, const uint_t* __restrict__ pairs,
                                                int* __restrict__ cnt) {
  __shared__ int c[128];
  int b = blockIdx.x, t = threadIdx.x;
  if (t < 128) c[t] = 0;
  __syncthreads();
  int n = min(bcnt[b], BCAP);
  for (int i = t; i < n; i += 256) atomicAdd(&c[pairs[b * BCAP + i] & 127], 1);
  __syncthreads();
  if (t < 128) {
    int node = b * 128 + t;
    if (node < NN) cnt[node] = c[t];
  }
}

__global__ __launch_bounds__(256) void dinv_k(const int* __restrict__ cnt, float* __restrict__ dinv) {
  int i = blockIdx.x * 256 + threadIdx.x;
  if (i < NN) dinv[i] = rsqrtf((float)(cnt[i] + 1));  // +1 self-loop; always > 0
}

__global__ __launch_bounds__(1024) void scan1(const int* __restrict__ cnt, int* __restrict__ rowstart,
                                              int* __restrict__ blocksum) {
  __shared__ int s[1024];
  int t = threadIdx.x;
  int i = blockIdx.x * 1024 + t;
  int v = (i < NN) ? cnt[i] : 0;
  s[t] = v;
  __syncthreads();
  for (int off = 1; off < 1024; off <<= 1) {
    int add = (t >= off) ? s[t - off] : 0;
    __syncthreads();
    s[t] += add;
    __syncthreads();
  }
  if (i < NN) rowstart[i] = s[t] - v;   // exclusive
  if (t == 1023) blocksum[blockIdx.x] = s[1023];
}

__global__ void scan2(int* blocksum, int nb) {
  if (threadIdx.x == 0 && blockIdx.x == 0) {
    int acc = 0;
    for (int b = 0; b < nb; ++b) { int v = blocksum[b]; blocksum[b] = acc; acc += v; }
  }
}

__global__ __launch_bounds__(1024) void scan3(int* __restrict__ rowstart, const int* __restrict__ blocksum) {
  int i = blockIdx.x * 1024 + threadIdx.x;
  if (i < NN) rowstart[i] += blocksum[blockIdx.x];
}

__global__ __launch_bounds__(256) void fill2_k(const int* __restrict__ bcnt, const uint_t* __restrict__ pairs,
                                               const int* __restrict__ rowstart, int* __restrict__ csr) {
  __shared__ int cur[128];
  int b = blockIdx.x, t = threadIdx.x;
  if (t < 128) cur[t] = 0;
  __syncthreads();
  int n = min(bcnt[b], BCAP);
  for (int i = t; i < n; i += 256) {
    uint_t p = pairs[b * BCAP + i];
    int lo = p & 127;
    int pos = rowstart[b * 128 + lo] + atomicAdd(&cur[lo], 1);
    csr[pos] = (int)(p >> 7);
  }
}

// ---------------- degree counting sort: perm[] groups equal-degree nodes ----------------

__global__ __launch_bounds__(256) void dhist_k(const int* __restrict__ cnt, int* __restrict__ dbin) {
  __shared__ int h[DBINS];
  int t = threadIdx.x;
  if (t < DBINS) h[t] = 0;
  __syncthreads();
  int i = blockIdx.x * 256 + t;
  if (i < NN) atomicAdd(&h[min(cnt[i], DBINS - 1)], 1);
  __syncthreads();
  if (t < DBINS && h[t]) atomicAdd(&dbin[t], h[t]);
}

__global__ void dscan_k(const int* __restrict__ dbin, int* __restrict__ dcur) {
  if (threadIdx.x == 0 && blockIdx.x == 0) {
    int acc = 0;
    for (int b = 0; b < DBINS; ++b) { dcur[b] = acc; acc += dbin[b]; }
  }
}

__global__ __launch_bounds__(256) void dplace_k(const int* __restrict__ cnt, int* __restrict__ dcur,
                                                int* __restrict__ perm) {
  __shared__ int h[DBINS];
  __shared__ int lbase[DBINS];
  int t = threadIdx.x;
  if (t < DBINS) h[t] = 0;
  __syncthreads();
  int i = blockIdx.x * 256 + t;
  int bin = 0, lrank = 0;
  if (i < NN) { bin = min(cnt[i], DBINS - 1); lrank = atomicAdd(&h[bin], 1); }
  __syncthreads();
  if (t < DBINS) lbase[t] = h[t] ? atomicAdd(&dcur[t], h[t]) : 0;
  __syncthreads();
  if (i < NN) perm[lbase[bin] + lrank] = i;
}

// ---------------- weight prep: transpose + bf16 hi/lo split (k-major rows) ----------------
// Wg1 (128x128) and Wl[0..9] (64x64 each); W2/Wf/W9 handled by ccomp_k.

__global__ __launch_bounds__(256) void wprep_k(const float* __restrict__ Wg1, const float* __restrict__ Wl,
                                               ushort_t* __restrict__ G1h, ushort_t* __restrict__ G1l,
                                               ushort_t* __restrict__ Lh, ushort_t* __restrict__ Ll) {
  int i = blockIdx.x * 256 + threadIdx.x;   // 0..57343
  if (i >= 57344) return;
  float w;
  ushort_t *ph, *pl;
  size_t di;
  if (i < 16384) {           // Wg1 128x128
    int k = i >> 7, n = i & 127;
    w = Wg1[i]; di = (size_t)n * 128 + k; ph = G1h; pl = G1l;
  } else {                   // Wl 10 x 64x64
    int i2 = i - 16384;
    int j = i2 >> 12, r = i2 & 4095;
    int k = r >> 6, n = r & 63;
    w = Wl[i2]; di = (size_t)j * 4096 + n * 64 + k; ph = Lh; pl = Ll;
  }
  ushort_t h = f2bf(w);
  ph[di] = h;
  pl[di] = f2bf(w - bf2f(h));
}

// ---------------- tail composition: Wc = [W2*Wf1 ; W9*Wf2] (192x64), bc = bf + b2*Wf1 + b9*Wf2 ----

__global__ __launch_bounds__(256) void ccomp_k(const float* __restrict__ W2, const float* __restrict__ W9,
                                               const float* __restrict__ Wf, const float* __restrict__ b2,
                                               const float* __restrict__ b9, const float* __restrict__ bfb,
                                               ushort_t* __restrict__ Fh, ushort_t* __restrict__ Fl,
                                               float* __restrict__ bc) {
  int i = blockIdx.x * 256 + threadIdx.x;   // 192*64 = 12288
  if (i >= 12288) return;
  int k = i >> 6, n = i & 63;
  float acc = 0.0f;
  if (k < 128) {
    for (int j = 0; j < 128; ++j) acc += W2[k * 128 + j] * Wf[j * 64 + n];
  } else {
    int k2 = k - 128;
    for (int j = 0; j < 64; ++j) acc += W9[k2 * 64 + j] * Wf[(128 + j) * 64 + n];
  }
  ushort_t h = f2bf(acc);
  Fh[(size_t)n * 192 + k] = h;
  Fl[(size_t)n * 192 + k] = f2bf(acc - bf2f(h));
  if (k == 0) {
    float b = bfb[n];
    for (int j = 0; j < 128; ++j) b += b2[j] * Wf[j * 64 + n];
    for (int j = 0; j < 64; ++j) b += b9[j] * Wf[(128 + j) * 64 + n];
    bc[n] = b;
  }
}

// ---------------- MFMA GEMM ----------------
// C[i,n] = bf16( dinv[i] * sum_k A[i,k] W[k,n] ).  64 rows/block, 4 waves.
// AF32: A is f32, split hi/lo in staging, 3-MFMA (~f32 accuracy).
// !AF32: A is bf16 already, 2-MFMA (A*Wh + A*Wl).  A = [A1 | A2] on K (K1,K2 multiples of 64).

template <int K1, int K2, int DC, bool AF32>
__global__ __launch_bounds__(256) void mgemm_k(const void* __restrict__ A1v, const void* __restrict__ A2v,
                                               const ushort_t* __restrict__ Wth, const ushort_t* __restrict__ Wtl,
                                               const float* __restrict__ dinv, ushort_t* __restrict__ C) {
  constexpr int K = K1 + K2;
  constexpr int NCH = K / 64;
  __shared__ ushort_t Ah[64 * 64];
  __shared__ ushort_t Al[AF32 ? 64 * 64 : 64];   // lo plane only for f32 A
  __shared__ ushort_t Wh[DC * 64], Wl_[DC * 64];
  const int t = threadIdx.x;
  const int row0 = blockIdx.x * 64;
  const int w = t >> 6, l = t & 63;
  const int lr = l & 15, kh = l >> 4;

  f32x4 acc[DC / 16];
  const f32x4 zz = {0.f, 0.f, 0.f, 0.f};
#pragma unroll
  for (int ct = 0; ct < DC / 16; ++ct) acc[ct] = zz;

  for (int kc = 0; kc < NCH; ++kc) {
    if (kc) __syncthreads();
    // ---- stage A chunk (64 rows x 64 k) ----
    if constexpr (AF32) {
#pragma unroll
      for (int it = 0; it < 4; ++it) {
        int idx = t + it * 256;
        int row = idx >> 4, kq = idx & 15;
        int gr = min(row0 + row, NN - 1);
        int kbase = kc * 64 + kq * 4;
        float4 a;
        if (K2 > 0 && kbase >= K1)
          a = *(const float4*)&((const float*)A2v)[(size_t)gr * K2 + kbase - K1];
        else
          a = *(const float4*)&((const float*)A1v)[(size_t)gr * K1 + kbase];
        ushort4 h, lo;
        h.x = f2bf(a.x); lo.x = f2bf(a.x - bf2f(h.x));
        h.y = f2bf(a.y); lo.y = f2bf(a.y - bf2f(h.y));
        h.z = f2bf(a.z); lo.z = f2bf(a.z - bf2f(h.z));
        h.w = f2bf(a.w); lo.w = f2bf(a.w - bf2f(h.w));
        int byt = (row * 128 + kq * 8) ^ ((row & 7) << 4);
        *(ushort4*)&Ah[byt >> 1] = h;
        *(ushort4*)&Al[byt >> 1] = lo;
      }
    } else {
#pragma unroll
      for (int it = 0; it < 2; ++it) {
        int idx = t + it * 256;
        int row = idx >> 3, kq = idx & 7;
        int gr = min(row0 + row, NN - 1);
        int kbase = kc * 64 + kq * 8;
        u16x8 v;
        if (K2 > 0 && kbase >= K1)
          v = *(const u16x8*)&((const ushort_t*)A2v)[(size_t)gr * K2 + kbase - K1];
        else
          v = *(const u16x8*)&((const ushort_t*)A1v)[(size_t)gr * K1 + kbase];
        int byt = (row * 128 + kq * 16) ^ ((row & 7) << 4);
        *(u16x8*)&Ah[byt >> 1] = v;
      }
    }
    // ---- stage W chunk (DC cols x 64 k), pre-split ----
    for (int idx = t; idx < DC * 8; idx += 256) {
      int n = idx >> 3, kq = idx & 7;
      u16x8 hv = *(const u16x8*)&Wth[(size_t)n * K + kc * 64 + kq * 8];
      u16x8 lv = *(const u16x8*)&Wtl[(size_t)n * K + kc * 64 + kq * 8];
      int byt = (n * 128 + kq * 16) ^ ((n & 7) << 4);
      *(u16x8*)&Wh[byt >> 1] = hv;
      *(u16x8*)&Wl_[byt >> 1] = lv;
    }
    __syncthreads();
    // ---- compute ----
#pragma unroll
    for (int kc2 = 0; kc2 < 2; ++kc2) {
      int arow = w * 16 + lr;
      int ab = (arow * 128 + kc2 * 64 + kh * 16) ^ ((arow & 7) << 4);
      bf16x8 ah = *(const bf16x8*)&Ah[ab >> 1];
      bf16x8 al;
      if constexpr (AF32) al = *(const bf16x8*)&Al[ab >> 1];
#pragma unroll
      for (int ct = 0; ct < DC / 16; ++ct) {
        int n = ct * 16 + lr;
        int bb = (n * 128 + kc2 * 64 + kh * 16) ^ ((n & 7) << 4);
        bf16x8 bh = *(const bf16x8*)&Wh[bb >> 1];
        bf16x8 bl = *(const bf16x8*)&Wl_[bb >> 1];
        if constexpr (AF32) acc[ct] = __builtin_amdgcn_mfma_f32_16x16x32_bf16(al, bh, acc[ct], 0, 0, 0);
        acc[ct] = __builtin_amdgcn_mfma_f32_16x16x32_bf16(ah, bl, acc[ct], 0, 0, 0);
        acc[ct] = __builtin_amdgcn_mfma_f32_16x16x32_bf16(ah, bh, acc[ct], 0, 0, 0);
      }
    }
  }
  // epilogue: C/D layout col=lane&15, row=(lane>>4)*4+reg
  float dv[4];
#pragma unroll
  for (int r = 0; r < 4; ++r) {
    int grow = row0 + w * 16 + kh * 4 + r;
    dv[r] = (grow < NN) ? dinv[grow] : 0.0f;
  }
#pragma unroll
  for (int ct = 0; ct < DC / 16; ++ct) {
    int col = ct * 16 + lr;
#pragma unroll
    for (int r = 0; r < 4; ++r) {
      int grow = row0 + w * 16 + kh * 4 + r;
      if (grow < NN) C[(size_t)grow * DC + col] = f2bf(acc[ct][r] * dv[r]);
    }
  }
}

// ---------------- aggregation (bf16 rows, f32 accum), degree-sorted via perm ----------------
// MODE 0: out bf16 = relu(acc*dinv + bias).  MODE 1: out f32 = sigmoid(acc*dinv + bias).

template <int D, int MODE>
__global__ __launch_bounds__(256) void agg_k(const uint4* __restrict__ t, const int* __restrict__ perm,
                                             const int* __restrict__ rowstart, const int* __restrict__ cnt,
                                             const int* __restrict__ csr, const float* __restrict__ dinv,
                                             const float* __restrict__ bias, void* __restrict__ outv) {
  constexpr int LPN = D / 8;
  int slot = blockIdx.x * (256 / LPN) + threadIdx.x / LPN;
  int lane = threadIdx.x % LPN;
  if (slot >= NN) return;
  int node = perm[slot];

  float acc[8];
  uint4 sv = t[(size_t)node * LPN + lane];
  {
    uint_t u[4] = {sv.x, sv.y, sv.z, sv.w};
#pragma unroll
    for (int q = 0; q < 4; ++q) {
      acc[2 * q]     = __uint_as_float(u[q] << 16);
      acc[2 * q + 1] = __uint_as_float(u[q] & 0xffff0000u);
    }
  }
  int s = rowstart[node], c = cnt[node];
  int j = 0;
  for (; j + 8 <= c; j += 8) {
    int idx[8];
#pragma unroll
    for (int u = 0; u < 8; ++u) idx[u] = csr[s + j + u];
    uint4 v[8];
#pragma unroll
    for (int u = 0; u < 8; ++u) v[u] = t[(size_t)idx[u] * LPN + lane];
#pragma unroll
    for (int u = 0; u < 8; ++u) {
      uint_t q0 = v[u].x, q1 = v[u].y, q2 = v[u].z, q3 = v[u].w;
      acc[0] += __uint_as_float(q0 << 16); acc[1] += __uint_as_float(q0 & 0xffff0000u);
      acc[2] += __uint_as_float(q1 << 16); acc[3] += __uint_as_float(q1 & 0xffff0000u);
      acc[4] += __uint_as_float(q2 << 16); acc[5] += __uint_as_float(q2 & 0xffff0000u);
      acc[6] += __uint_as_float(q3 << 16); acc[7] += __uint_as_float(q3 & 0xffff0000u);
    }
  }
  for (; j < c; ++j) {
    int sn = csr[s + j];
    uint4 v = t[(size_t)sn * LPN + lane];
    uint_t q0 = v.x, q1 = v.y, q2 = v.z, q3 = v.w;
    acc[0] += __uint_as_float(q0 << 16); acc[1] += __uint_as_float(q0 & 0xffff0000u);
    acc[2] += __uint_as_float(q1 << 16); acc[3] += __uint_as_float(q1 & 0xffff0000u);
    acc[4] += __uint_as_float(q2 << 16); acc[5] += __uint_as_float(q2 & 0xffff0000u);
    acc[6] += __uint_as_float(q3 << 16); acc[7] += __uint_as_float(q3 & 0xffff0000u);
  }
  float dv = dinv[node];
  if constexpr (MODE == 0) {
    u16x8 ov;
#pragma unroll
    for (int q = 0; q < 8; ++q) {
      float o = fmaxf(acc[q] * dv + bias[lane * 8 + q], 0.0f);
      ov[q] = f2bf(o);
    }
    *(u16x8*)&((ushort_t*)outv)[(size_t)node * D + lane * 8] = ov;
  } else {
    float o[8];
#pragma unroll
    for (int q = 0; q < 8; ++q) {
      float v2 = acc[q] * dv + bias[lane * 8 + q];
      o[q] = 1.0f / (1.0f + __expf(-v2));
    }
    float4 o0 = {o[0], o[1], o[2], o[3]};
    float4 o1 = {o[4], o[5], o[6], o[7]};
    float* outf = (float*)outv;
    *(float4*)&outf[(size_t)node * D + lane * 8] = o0;
    *(float4*)&outf[(size_t)node * D + lane * 8 + 4] = o1;
  }
}

// ---------------- launch ----------------

extern "C" void kernel_launch(void* const* d_in, const int* in_sizes, int n_in,
                              void* d_out, int out_size, void* d_ws, size_t ws_size,
                              hipStream_t stream) {
  const float* x  = (const float*)d_in[0];
  const float* y  = (const float*)d_in[1];
  const int* ei   = (const int*)d_in[2];
  const float* Wg1 = (const float*)d_in[3];
  const float* bg1 = (const float*)d_in[4];
  const float* Wg2 = (const float*)d_in[5];
  const float* bg2 = (const float*)d_in[6];   // folded into bc
  const float* Wl  = (const float*)d_in[7];
  const float* bl  = (const float*)d_in[8];
  const float* Wf  = (const float*)d_in[9];
  const float* bf  = (const float*)d_in[10];
  float* out = (float*)d_out;

  char* ws = (char*)d_ws;
  size_t off = 0;
  auto alloc = [&](size_t bytes) { void* p = ws + off; off += (bytes + 511) & ~(size_t)511; return p; };
  int* cnt      = (int*)alloc((size_t)NN * 4);
  int* rowstart = (int*)alloc((size_t)NN * 4);
  int* blocksum = (int*)alloc(512);
  float* dinv   = (float*)alloc((size_t)NN * 4);
  int* csr      = (int*)alloc((size_t)NE * 4);
  int* bcnt     = (int*)alloc((size_t)NB * 4);
  uint_t* pairs = (uint_t*)alloc((size_t)NB * BCAP * 4);
  int* perm     = (int*)alloc((size_t)NN * 4);
  int* dbin     = (int*)alloc(DBINS * 4);
  int* dcur     = (int*)alloc(DBINS * 4);
  ushort_t* Tb  = (ushort_t*)alloc((size_t)NN * 128 * 2);  // conv1 staging; halves = xlA/xlB later
  ushort_t* H   = (ushort_t*)alloc((size_t)NN * 128 * 2);  // feature h (bf16)
  ushort_t* Ub  = (ushort_t*)alloc((size_t)NN * 64 * 2);   // per-layer GEMM->agg staging
  ushort_t* G1h = (ushort_t*)alloc(128 * 128 * 2);
  ushort_t* G1l = (ushort_t*)alloc(128 * 128 * 2);
  ushort_t* Lh  = (ushort_t*)alloc(10 * 64 * 64 * 2);
  ushort_t* Ll  = (ushort_t*)alloc(10 * 64 * 64 * 2);
  ushort_t* Fh  = (ushort_t*)alloc(64 * 192 * 2);          // composed tail weight (k-major)
  ushort_t* Fl  = (ushort_t*)alloc(64 * 192 * 2);
  float* bc     = (float*)alloc(64 * 4);                   // composed tail bias
  ushort_t* xlA = Tb;                     // label ping (Tb dead after conv1 agg)
  ushort_t* xlB = Tb + (size_t)NN * 64;   // label pong

  const int* esrc = ei;
  const int* edst = ei + NE;

  wprep_k<<<224, 256, 0, stream>>>(Wg1, Wl, G1h, G1l, Lh, Ll);
  ccomp_k<<<48, 256, 0, stream>>>(Wg2, Wl + (size_t)9 * 4096, Wf, bg2, bl + (size_t)9 * 64, bf, Fh, Fl, bc);
  hipMemsetAsync(bcnt, 0, (size_t)NB * 4, stream);
  hipMemsetAsync(dbin, 0, DBINS * 4, stream);
  bucketA_k<<<BKBLK, 512, 0, stream>>>(esrc, edst, bcnt, pairs);
  count2_k<<<NB, 256, 0, stream>>>(bcnt, pairs, cnt);
  dinv_k<<<(NN + 255) / 256, 256, 0, stream>>>(cnt, dinv);
  scan1<<<98, 1024, 0, stream>>>(cnt, rowstart, blocksum);
  scan2<<<1, 1, 0, stream>>>(blocksum, 98);
  scan3<<<98, 1024, 0, stream>>>(rowstart, blocksum);
  fill2_k<<<NB, 256, 0, stream>>>(bcnt, pairs, rowstart, csr);
  dhist_k<<<(NN + 255) / 256, 256, 0, stream>>>(cnt, dbin);
  dscan_k<<<1, 64, 0, stream>>>(dbin, dcur);
  dplace_k<<<(NN + 255) / 256, 256, 0, stream>>>(cnt, dcur, perm);

  const int GG = (NN + 63) / 64;

  // feature conv1: h = relu(S(x W1) + b1)   [conv2 folded into tail]
  mgemm_k<128, 0, 128, true><<<GG, 256, 0, stream>>>(x, nullptr, G1h, G1l, dinv, Tb);
  agg_k<128, 0><<<NN / 16, 256, 0, stream>>>((const uint4*)Tb, perm, rowstart, cnt, csr, dinv, bg1, H);

  // label branch: layers j=0..8 (all relu); j=9 folded into tail
  const void* in = y;
  for (int j = 0; j < 9; ++j) {
    ushort_t* nxt = (j & 1) ? xlB : xlA;
    if (j == 0)
      mgemm_k<64, 0, 64, true><<<GG, 256, 0, stream>>>(in, nullptr, Lh, Ll, dinv, Ub);
    else
      mgemm_k<64, 0, 64, false><<<GG, 256, 0, stream>>>(in, nullptr, Lh + (size_t)j * 4096, Ll + (size_t)j * 4096, dinv, Ub);
    agg_k<64, 0><<<NN / 32, 256, 0, stream>>>((const uint4*)Ub, perm, rowstart, cnt, csr, dinv, bl + (size_t)j * 64, nxt);
    in = nxt;
  }

  // tail: z = sigmoid( S([h | xl9] Wc) + bc )   (xl9 in xlA: j=8 even)
  mgemm_k<128, 64, 64, false><<<GG, 256, 0, stream>>>(H, xlA, Fh, Fl, dinv, Ub);
  agg_k<64, 1><<<NN / 32, 256, 0, stream>>>((const uint4*)Ub, perm, rowstart, cnt, csr, dinv, bc, out);
}